// Round 7
// baseline (296.382 us; speedup 1.0000x reference)
//
#include <hip/hip_runtime.h>
#include <hip/hip_bf16.h>
#include <math.h>

#define N_NODES 50000
#define N_EDGES 800000
#define FDIM 128
#define D2_BLOCKS 196     // ceil(50000/256) — all co-resident on 256 CUs
#define XW_BLOCKS 391     // ceil(50000/128) row-tiles of 32 x 4 waves
#define HIST_BLOCKS 3125  // 800000/256 exactly

typedef unsigned int uint32;
typedef __attribute__((ext_vector_type(8))) __bf16 bf16x8;
typedef __attribute__((ext_vector_type(8))) short short8;
typedef __attribute__((ext_vector_type(16))) float f32x16;

// sync[] layout (ints):
// [0] evolve-done counter (D1) ; [1..4] D2 barrier counters
// [8..8+196) raw block sums ; [208..208+196) scanned exclusive block bases
#define EVOLVE_DONE 0
#define BAR0 1
#define SUMS 8
#define SCANNED 208

// round-to-nearest-even fp32 -> bf16 bits (finite inputs)
__device__ inline unsigned short f2bf(float f) {
  unsigned int u = __float_as_uint(f);
  unsigned int r = u + 0x7fffu + ((u >> 16) & 1u);
  return (unsigned short)(r >> 16);
}

// ---------------------------------------------------------------------------
// D1 mega-kernel:
//   blocks [0,128):       evolve W row (then fall through to xw)
//   blocks [0,XW_BLOCKS): spin on evolve-done, then MFMA y = bf16(x @ W)
//   blocks [XW_BLOCKS..): rank histogram (1 atomic/edge), starts immediately
// Blocks 0..390 are co-resident (32KB LDS -> 5 blocks/CU -> capacity 1280),
// so the spin cannot deadlock.
// ---------------------------------------------------------------------------
__global__ __launch_bounds__(256) void mega1_kernel(
    const float* __restrict__ W0, const float* __restrict__ Wih,
    const float* __restrict__ Whh, const float* __restrict__ bih,
    const float* __restrict__ bhh, float* __restrict__ W,
    const int* __restrict__ ei, int* __restrict__ cnt, int* __restrict__ rank,
    const float* __restrict__ x, unsigned short* __restrict__ y,
    int* __restrict__ sync, int n) {
  __shared__ __align__(16) char smem[32768];
  int t = threadIdx.x;
  int bid = blockIdx.x;

  if (bid >= XW_BLOCKS) {
    // ---- hist path ----
    int idx = (bid - XW_BLOCKS) * 256 + t;
    if (idx < N_EDGES) {
      int dst = ei[N_EDGES + idx];
      rank[idx] = atomicAdd(&cnt[dst], 1);
    }
    return;
  }

  if (bid < FDIM) {
    // ---- evolve phase: this block computes W row `bid` ----
    float* w0s = (float*)smem;        // 128
    float* gis = w0s + FDIM;          // 384
    float* ghs = gis + 3 * FDIM;      // 384
    if (t < FDIM) w0s[t] = W0[bid * FDIM + t];
    __syncthreads();
    for (int jj = t; jj < 3 * FDIM; jj += 256) {
      float gi = bih[jj], gh = bhh[jj];
      const float4* wih4 = (const float4*)(Wih + jj * FDIM);
      const float4* whh4 = (const float4*)(Whh + jj * FDIM);
#pragma unroll 8
      for (int k = 0; k < FDIM / 4; k++) {
        float4 a = wih4[k];
        float4 b = whh4[k];
        float w0a = w0s[4 * k], w0b = w0s[4 * k + 1];
        float w0c = w0s[4 * k + 2], w0d = w0s[4 * k + 3];
        gi += a.x * w0a + a.y * w0b + a.z * w0c + a.w * w0d;
        gh += b.x * w0a + b.y * w0b + b.z * w0c + b.w * w0d;
      }
      gis[jj] = gi;
      ghs[jj] = gh;
    }
    __syncthreads();
    if (t < FDIM) {
      float r = 1.0f / (1.0f + expf(-(gis[t] + ghs[t])));
      float z = 1.0f / (1.0f + expf(-(gis[t + FDIM] + ghs[t + FDIM])));
      float nn = tanhf(gis[t + 2 * FDIM] + r * ghs[t + 2 * FDIM]);
      W[bid * FDIM + t] = (1.0f - z) * nn + z * w0s[t];
      __threadfence();  // device-visible before the release add below
    }
    __syncthreads();
    if (t == 0)
      __hip_atomic_fetch_add(&sync[EVOLVE_DONE], 1, __ATOMIC_ACQ_REL,
                             __HIP_MEMORY_SCOPE_AGENT);
  }

  // ---- xw path: wait for full W ----
  if (t == 0) {
    while (__hip_atomic_load(&sync[EVOLVE_DONE], __ATOMIC_ACQUIRE,
                             __HIP_MEMORY_SCOPE_AGENT) < FDIM) {
      __builtin_amdgcn_s_sleep(2);
    }
  }
  __syncthreads();

  // stage W -> LDS (bf16, frag-blocked): Bs[kg][n][j] = W[kg*8+j][n]
  short* Bs = (short*)smem;
#pragma unroll
  for (int i = 0; i < 64; i++) {
    int idx = i * 256 + t;  // coalesced read of W[k][n]
    int k = idx >> 7, nn = idx & 127;
    Bs[(((k >> 3) << 7) + nn) * 8 + (k & 7)] = (short)f2bf(W[idx]);
  }
  __syncthreads();

  int lane = t & 63;
  int wid = bid * 4 + (t >> 6);
  int tr = wid * 32;  // tile row base
  if (tr >= n) return;
  int m = lane & 31;   // A row / D col within tile
  int q2 = lane >> 5;  // half-wave: k-offset selector

  int row = tr + m;
  if (row >= n) row = n - 1;  // tail clamp (stores are guarded)
  const float* xr = x + (size_t)row * FDIM;

  bf16x8 a[8];
#pragma unroll
  for (int kc = 0; kc < 8; kc++) {
    int k0 = kc * 16 + q2 * 8;
    float4 p = *(const float4*)(xr + k0);
    float4 q = *(const float4*)(xr + k0 + 4);
    short8 s;
    s[0] = (short)f2bf(p.x); s[1] = (short)f2bf(p.y);
    s[2] = (short)f2bf(p.z); s[3] = (short)f2bf(p.w);
    s[4] = (short)f2bf(q.x); s[5] = (short)f2bf(q.y);
    s[6] = (short)f2bf(q.z); s[7] = (short)f2bf(q.w);
    a[kc] = __builtin_bit_cast(bf16x8, s);
  }

  f32x16 acc[4];
#pragma unroll
  for (int ct = 0; ct < 4; ct++) {
#pragma unroll
    for (int r = 0; r < 16; r++) acc[ct][r] = 0.0f;
  }
#pragma unroll
  for (int ct = 0; ct < 4; ct++) {
    int nn = ct * 32 + m;
#pragma unroll
    for (int kc = 0; kc < 8; kc++) {
      int kg = kc * 2 + q2;
      bf16x8 b = __builtin_bit_cast(
          bf16x8, *(const short8*)(Bs + (((kg << 7) + nn) << 3)));
      acc[ct] = __builtin_amdgcn_mfma_f32_32x32x16_bf16(a[kc], b, acc[ct], 0,
                                                        0, 0);
    }
  }

  // D layout: col = lane&31, row = (reg&3) + 8*(reg>>2) + 4*(lane>>5)
#pragma unroll
  for (int r = 0; r < 16; r++) {
    int rl = (r & 3) + ((r >> 2) << 3) + (q2 << 2);
    int rg = tr + rl;
    if (rg < n) {
#pragma unroll
      for (int ct = 0; ct < 4; ct++) {
        y[(size_t)rg * FDIM + ct * 32 + m] = f2bf(acc[ct][r]);
      }
    }
  }
}

// ---------------------------------------------------------------------------
// D2 grid barrier: 196 co-resident blocks, release/acquire counter.
// ---------------------------------------------------------------------------
__device__ inline void grid_bar(int* ctr, int t) {
  __syncthreads();
  if (t == 0) {
    __hip_atomic_fetch_add(ctr, 1, __ATOMIC_ACQ_REL, __HIP_MEMORY_SCOPE_AGENT);
    while (__hip_atomic_load(ctr, __ATOMIC_ACQUIRE,
                             __HIP_MEMORY_SCOPE_AGENT) < D2_BLOCKS) {
      __builtin_amdgcn_s_sleep(1);
    }
  }
  __syncthreads();
}

// ---------------------------------------------------------------------------
// D2 mega-kernel (196 blocks x 256):
//  P1 local scan -> lexcl, block sums
//  P2 block 0 scans the 196 partials
//  P3 write offs; scatter edges to CSR (pos = scanned[dst>>8]+lexcl[dst]+rank)
//  P4 deg from CSR -> dinv
//  P5 fixup: csr_w <- w * dinv[src] * dinv[dst]  (full GCN norm)
// ---------------------------------------------------------------------------
__global__ __launch_bounds__(256) void mega2_kernel(
    const int* __restrict__ ei, const float* __restrict__ ew,
    const int* __restrict__ cnt, const int* __restrict__ rank,
    int* __restrict__ sync, int* __restrict__ lexcl, int* __restrict__ offs,
    int2* csr, float* __restrict__ dinv, int n) {
  __shared__ int tmp[256];
  int t = threadIdx.x, bid = blockIdx.x;
  const int STRIDE = D2_BLOCKS * 256;  // 50176
  int idx = bid * 256 + t;

  // P1: local exclusive scan of cnt
  int v = (idx < n) ? cnt[idx] : 0;
  tmp[t] = v;
  __syncthreads();
#pragma unroll
  for (int off = 1; off < 256; off <<= 1) {
    int u = (t >= off) ? tmp[t - off] : 0;
    __syncthreads();
    tmp[t] += u;
    __syncthreads();
  }
  if (idx < n) lexcl[idx] = tmp[t] - v;
  if (t == 255) sync[SUMS + bid] = tmp[255];
  grid_bar(&sync[BAR0 + 0], t);

  // P2: block 0 scans the partials
  if (bid == 0) {
    int pv = (t < D2_BLOCKS) ? sync[SUMS + t] : 0;
    tmp[t] = pv;
    __syncthreads();
#pragma unroll
    for (int off = 1; off < 256; off <<= 1) {
      int u = (t >= off) ? tmp[t - off] : 0;
      __syncthreads();
      tmp[t] += u;
      __syncthreads();
    }
    if (t < D2_BLOCKS) sync[SCANNED + t] = tmp[t] - pv;
    if (t == D2_BLOCKS - 1) offs[n] = tmp[t];  // total = N_EDGES
  }
  grid_bar(&sync[BAR0 + 1], t);

  // P3: offs + scatter
  for (int i = idx; i < n; i += STRIDE)
    offs[i] = sync[SCANNED + (i >> 8)] + lexcl[i];
  for (int j = idx; j < N_EDGES; j += STRIDE) {
    int src = ei[j];
    int dst = ei[N_EDGES + j];
    int pos = sync[SCANNED + (dst >> 8)] + lexcl[dst] + rank[j];
    csr[pos] = make_int2(src, __float_as_int(ew[j]));
  }
  grid_bar(&sync[BAR0 + 2], t);

  // P4: deg -> dinv
  for (int i = idx; i < n; i += STRIDE) {
    int b = offs[i], e = offs[i + 1];
    float d = 1.0f;
    for (int j = b; j < e; j++) d += __int_as_float(csr[j].y);
    dinv[i] = (d > 0.0f) ? rsqrtf(d) : 0.0f;
  }
  grid_bar(&sync[BAR0 + 3], t);

  // P5: fixup csr weights to full norm
  for (int i = idx; i < n; i += STRIDE) {
    float dd = dinv[i];
    int b = offs[i], e = offs[i + 1];
    for (int j = b; j < e; j++) {
      int2 c = csr[j];
      csr[j].y = __float_as_int(__int_as_float(c.y) * dinv[c.x] * dd);
    }
  }
}

// ---------------------------------------------------------------------------
// D3: per-node gather (bf16 y rows) + tanh + w_lin dot + bias.
// h[dst] = tanh( dinv_d^2 * y[dst] + sum_e wnorm_e * y[src_e] )
// csr weights are fully normalized; inner loop has no dinv loads.
// ---------------------------------------------------------------------------
__global__ __launch_bounds__(256) void gather_kernel(
    const uint32* __restrict__ yb, const int* __restrict__ offs,
    const int2* __restrict__ csr, const float* __restrict__ dinv,
    const float* __restrict__ wl, const float* __restrict__ bl,
    float* __restrict__ out, int n) {
  int wid = (int)((blockIdx.x * (size_t)blockDim.x + threadIdx.x) >> 6);
  int lane = threadIdx.x & 63;
  if (wid >= n) return;
  float di = dinv[wid];
  float sn = di * di;  // self-loop norm
  uint32 uv = yb[(size_t)wid * 64 + lane];
  float ax = sn * __uint_as_float(uv << 16);
  float ay = sn * __uint_as_float(uv & 0xffff0000u);
  int beg = offs[wid], end = offs[wid + 1];
  int e = beg;
  for (; e + 8 <= end; e += 8) {
    int2 c[8];
    uint32 u[8];
#pragma unroll
    for (int q = 0; q < 8; q++) c[q] = csr[e + q];
#pragma unroll
    for (int q = 0; q < 8; q++) u[q] = yb[(size_t)c[q].x * 64 + lane];
#pragma unroll
    for (int q = 0; q < 8; q++) {
      float wn = __int_as_float(c[q].y);
      ax += wn * __uint_as_float(u[q] << 16);
      ay += wn * __uint_as_float(u[q] & 0xffff0000u);
    }
  }
  for (; e < end; e++) {
    int2 c = csr[e];
    uint32 u = yb[(size_t)c.x * 64 + lane];
    float wn = __int_as_float(c.y);
    ax += wn * __uint_as_float(u << 16);
    ay += wn * __uint_as_float(u & 0xffff0000u);
  }
  float2 wv = ((const float2*)wl)[lane];
  float p = tanhf(ax) * wv.x + tanhf(ay) * wv.y;
#pragma unroll
  for (int o = 32; o > 0; o >>= 1) p += __shfl_down(p, o, 64);
  if (lane == 0) out[wid] = p + bl[0];
}

// ---------------------------------------------------------------------------
extern "C" void kernel_launch(void* const* d_in, const int* in_sizes, int n_in,
                              void* d_out, int out_size, void* d_ws,
                              size_t ws_size, hipStream_t stream) {
  const float* x = (const float*)d_in[0];     // (N,128)
  const int* ei = (const int*)d_in[1];        // (2,E)
  const float* ew = (const float*)d_in[2];    // (E,)
  const float* W0 = (const float*)d_in[3];    // (128,128)
  const float* Wih = (const float*)d_in[4];   // (384,128)
  const float* Whh = (const float*)d_in[5];   // (384,128)
  const float* bih = (const float*)d_in[6];   // (384,)
  const float* bhh = (const float*)d_in[7];   // (384,)
  const float* wl = (const float*)d_in[8];    // (1,128)
  const float* bl = (const float*)d_in[9];    // (1,)
  float* out = (float*)d_out;                 // (N,1)

  // Workspace layout (cnt and sync adjacent -> one memset)
  float* ws = (float*)d_ws;
  float* W_ev = ws;                                      // 16384 f
  unsigned short* y = (unsigned short*)(W_ev + 16384);   // N*128 bf16
  float* dinv = (float*)(y + (size_t)N_NODES * FDIM);    // 50000 f
  int* cnt = (int*)(dinv + N_NODES);                     // 50000 i
  int* sync = cnt + N_NODES;                             // 512 i
  int* rank = sync + 512;                                // 800000 i
  int* lexcl = rank + N_EDGES;                           // 50000 i
  int* offs = lexcl + N_NODES;                           // 50004 i (padded to 50008)
  int2* csr = (int2*)(offs + 50008);                     // 800000 int2

  // M0: zero cnt + sync counters (one contiguous fill)
  hipMemsetAsync(cnt, 0, sizeof(int) * (N_NODES + 512), stream);
  // D1: evolve + xw-MFMA + rank histogram (fused)
  mega1_kernel<<<XW_BLOCKS + HIST_BLOCKS, 256, 0, stream>>>(
      W0, Wih, Whh, bih, bhh, W_ev, ei, cnt, rank, x, y, sync, N_NODES);
  // D2: scan + scatter + deg/dinv + csr-norm fixup (fused, 4 grid barriers)
  mega2_kernel<<<D2_BLOCKS, 256, 0, stream>>>(ei, ew, cnt, rank, sync, lexcl,
                                              offs, csr, dinv, N_NODES);
  // D3: fused gather + tanh + linear
  gather_kernel<<<(N_NODES * 64) / 256, 256, 0, stream>>>(
      (const uint32*)y, offs, csr, dinv, wl, bl, out, N_NODES);
}